// Round 8
// baseline (3288.265 us; speedup 1.0000x reference)
//
#include <hip/hip_runtime.h>
#include <hip/hip_bf16.h>
#include <type_traits>

#define BB 64
#define TT 512
#define DD 1024
#define UU 1024

typedef __attribute__((ext_vector_type(8))) short short8;
typedef __attribute__((ext_vector_type(4))) float f32x4;
typedef __attribute__((ext_vector_type(4))) unsigned short us4;

static __device__ __forceinline__ unsigned short f2bf(float f) {
    unsigned int u = __float_as_uint(f);
    unsigned int r = (u + 0x7fffu + ((u >> 16) & 1u)) >> 16;   // RNE
    return (unsigned short)r;
}
static __device__ __forceinline__ float bf2f(unsigned short s) {
    return __uint_as_float(((unsigned int)s) << 16);
}

// ---------------------------------------------------------------------------
// Pack a logical (1024 x 4096) weight [k][gate*1024+u] into MFMA B-fragment
// layout: out[((n16*32 + kb)*64 + lane)*8 + i] =
//         W[kb*32 + (lane>>4)*8 + i][n16*16 + (lane&15)]
// ---------------------------------------------------------------------------
__global__ __launch_bounds__(256) void pack_w(
    const float* __restrict__ w0, const float* __restrict__ w1,
    const float* __restrict__ w2, const float* __restrict__ w3,
    short* __restrict__ out)
{
    int tid = blockIdx.x * 256 + threadIdx.x;   // 524288 threads
    int lane = tid & 63;
    int kb = (tid >> 6) & 31;
    int n16 = tid >> 11;
    int col = (n16 << 4) + (lane & 15);
    int g = col >> 10, u = col & 1023;
    const float* __restrict__ src = (g == 0) ? w0 : (g == 1) ? w1 : (g == 2) ? w2 : w3;
    int kbase = kb * 32 + ((lane >> 4) << 3);
    short8 p;
#pragma unroll
    for (int i = 0; i < 8; ++i) p[i] = (short)f2bf(src[(size_t)(kbase + i) * UU + u]);
    *reinterpret_cast<short8*>(out + (size_t)tid * 8) = p;
}

// ---------------------------------------------------------------------------
__global__ __launch_bounds__(256) void init_hbf(const float* __restrict__ h0,
                                                unsigned short* __restrict__ hb)
{
    int i = blockIdx.x * 256 + threadIdx.x;  // 65536
    hb[i] = f2bf(h0[i & (UU - 1)]);
}

// ---------------------------------------------------------------------------
// Phase 1: xw = x @ [fw|iw|cw|ow] + bias, MFMA bf16.
// Output layout: xw[t][ublk(64)][b(64)][g(4)][u16(16)]
// ---------------------------------------------------------------------------
template <typename XT>
__global__ __launch_bounds__(256) void gemm_xw(
    const float* __restrict__ x, const short* __restrict__ wpk,
    const float* __restrict__ fb, const float* __restrict__ ib,
    const float* __restrict__ cb, const float* __restrict__ ob,
    XT* __restrict__ xw)
{
    __shared__ short As[128 * 40];   // 128 rows x (32 + 8 pad) bf16
    __shared__ short Bs[8 * 512];    // 8 n16-tiles x 512

    const int tid = threadIdx.x;
    const int lane = tid & 63;
    const int wid = tid >> 6;
    const int wr = wid >> 1, wc = wid & 1;
    const int n0 = blockIdx.x << 7;
    const int m0 = blockIdx.y << 7;
    const int n16b = n0 >> 4;

    const int srow = tid >> 1;
    const int kh = tid & 1;
    const float* __restrict__ xrow = x + (size_t)(m0 + srow) * DD + kh * 16;
    const short* __restrict__ wsrc =
        wpk + ((size_t)(n16b + (tid >> 5)) * 32) * 512 + (size_t)(tid & 31) * 16;

    f32x4 acc[4][4];
#pragma unroll
    for (int i = 0; i < 4; ++i)
#pragma unroll
        for (int j = 0; j < 4; ++j) acc[i][j] = (f32x4){0.f, 0.f, 0.f, 0.f};

    const int aoff = (wr * 64 + (lane & 15)) * 40 + (lane >> 4) * 8;
    const int boff = (wc * 4) * 512 + lane * 8;

    for (int kb = 0; kb < 32; ++kb) {
        const float4* xp = reinterpret_cast<const float4*>(xrow + kb * 32);
        float4 v0 = xp[0], v1 = xp[1], v2 = xp[2], v3 = xp[3];
        short8 p0, p1;
        p0[0] = (short)f2bf(v0.x); p0[1] = (short)f2bf(v0.y);
        p0[2] = (short)f2bf(v0.z); p0[3] = (short)f2bf(v0.w);
        p0[4] = (short)f2bf(v1.x); p0[5] = (short)f2bf(v1.y);
        p0[6] = (short)f2bf(v1.z); p0[7] = (short)f2bf(v1.w);
        p1[0] = (short)f2bf(v2.x); p1[1] = (short)f2bf(v2.y);
        p1[2] = (short)f2bf(v2.z); p1[3] = (short)f2bf(v2.w);
        p1[4] = (short)f2bf(v3.x); p1[5] = (short)f2bf(v3.y);
        p1[6] = (short)f2bf(v3.z); p1[7] = (short)f2bf(v3.w);
        *reinterpret_cast<short8*>(&As[srow * 40 + kh * 16]) = p0;
        *reinterpret_cast<short8*>(&As[srow * 40 + kh * 16 + 8]) = p1;

        const short8* ws8 = reinterpret_cast<const short8*>(wsrc + (size_t)kb * 512);
        short8 b0v = ws8[0], b1v = ws8[1];
        *reinterpret_cast<short8*>(&Bs[tid * 16]) = b0v;
        *reinterpret_cast<short8*>(&Bs[tid * 16 + 8]) = b1v;
        __syncthreads();

        short8 af[4], bfr[4];
#pragma unroll
        for (int fi = 0; fi < 4; ++fi)
            af[fi] = *reinterpret_cast<const short8*>(&As[aoff + fi * 640]);
#pragma unroll
        for (int fj = 0; fj < 4; ++fj)
            bfr[fj] = *reinterpret_cast<const short8*>(&Bs[boff + fj * 512]);
#pragma unroll
        for (int fi = 0; fi < 4; ++fi)
#pragma unroll
            for (int fj = 0; fj < 4; ++fj)
                acc[fi][fj] = __builtin_amdgcn_mfma_f32_16x16x32_bf16(
                    af[fi], bfr[fj], acc[fi][fj], 0, 0, 0);
        __syncthreads();
    }

    const int g = n0 >> 10;
    const float* __restrict__ bias = (g == 0) ? fb : (g == 1) ? ib : (g == 2) ? cb : ob;
#pragma unroll
    for (int fi = 0; fi < 4; ++fi) {
#pragma unroll
        for (int fj = 0; fj < 4; ++fj) {
            int n = n0 + wc * 64 + fj * 16 + (lane & 15);
            int uc = n & 1023;
            int ub = uc >> 4, ul = uc & 15;
            float bv = bias[uc];
#pragma unroll
            for (int r = 0; r < 4; ++r) {
                int row = m0 + wr * 64 + fi * 16 + (lane >> 4) * 4 + r;
                int b = row >> 9, t = row & 511;
                float v = acc[fi][fj][r] + bv;
                size_t off = (((size_t)t * 64 + ub) * BB + b) * 64 + g * 16 + ul;
                if constexpr (std::is_same<XT, float>::value) xw[off] = v;
                else xw[off] = (XT)f2bf(v);
            }
        }
    }
}

// ---------------------------------------------------------------------------
// Phase 2: persistent scan. Grid 256 = 4 m-groups (16 batch rows) x 64
// u-blocks. Block 256 thr = 4 waves; wave = gate (U B-frags in VGPRs).
// Wave specialization per step:
//   wave 1: polls next-step flags (overlaps producers' store+drain+flag)
//   all:    DMA-stage h_t (global_load_lds sc1, rotating buffer), MFMA, gbuf
//   wave 0: tail for all 16x16 cells (4/lane) -> sc1 h-stores -> flag -> y
// ---------------------------------------------------------------------------
template <typename XT>
__global__ __launch_bounds__(256, 1) void lstm_scan(
    const XT* __restrict__ xw, const float* __restrict__ h0,
    unsigned short* __restrict__ hrot,     // [TT+1][64][1024] bf16 rotating
    const short* __restrict__ upk,
    float* __restrict__ y, int* __restrict__ flg)   // [TT+1][4][64]
{
    __shared__ unsigned short hls[16 * 1032 + 8];   // 16 rows, 1032-short pitch
    __shared__ float gbuf[4][16][20];               // pitch 20 -> 2-way (free)

    const int tid = threadIdx.x;
    const int lane = tid & 63;
    const int gi = tid >> 6;              // wave = gate
    const int mz = blockIdx.x >> 6;       // m-group 0..3
    const int ub = blockIdx.x & 63;       // u column-block
    const int r0 = mz << 4;               // first batch row
    const int u0 = ub << 4;

    // B-fragments for (gate gi, n16 = gi*64+ub), all 32 k-groups -> VGPRs
    const short* __restrict__ bsrc =
        upk + ((size_t)(gi * 64 + ub) * 32) * 512 + (size_t)lane * 8;
    short8 bfr[32];
#pragma unroll
    for (int kb = 0; kb < 32; ++kb)
        bfr[kb] = *reinterpret_cast<const short8*>(bsrc + (size_t)kb * 512);

    const int aoff = (lane & 15) * 1032 + (lane >> 4) * 8;  // LDS A-frag (shorts)

    // wave-0 tail mapping: lane -> (row = lane>>2, cols cb..cb+3)
    const int trow = lane >> 2;
    const int cb = (lane & 3) << 2;
    float h_own[4];
#pragma unroll
    for (int j = 0; j < 4; ++j) h_own[j] = h0[u0 + cb + j];

    for (int t = 0; t < TT; ++t) {
        if (t > 0) {
            if (gi == 1) {
                const int* fl = flg + ((size_t)t * 4 + mz) * 64 + lane;
                while (__hip_atomic_load(fl, __ATOMIC_RELAXED,
                                         __HIP_MEMORY_SCOPE_AGENT) == 0)
                    __builtin_amdgcn_s_sleep(1);
            }
            __syncthreads();
        }

        // wave 0: xw operand loads for the tail (complete under MFMA)
        float xvv[4][4];
        if (gi == 0) {
            if constexpr (std::is_same<XT, float>::value) {
                const float* xp = (const float*)xw + ((size_t)t * 64 + ub) * 4096
                                  + (size_t)(r0 + trow) * 64 + cb;
#pragma unroll
                for (int g = 0; g < 4; ++g) {
                    f32x4 v = *reinterpret_cast<const f32x4*>(xp + g * 16);
#pragma unroll
                    for (int j = 0; j < 4; ++j) xvv[g][j] = v[j];
                }
            } else {
                const unsigned short* xp = (const unsigned short*)xw
                                  + ((size_t)t * 64 + ub) * 4096
                                  + (size_t)(r0 + trow) * 64 + cb;
#pragma unroll
                for (int g = 0; g < 4; ++g) {
                    us4 v = *reinterpret_cast<const us4*>(xp + g * 16);
#pragma unroll
                    for (int j = 0; j < 4; ++j) xvv[g][j] = bf2f(v[j]);
                }
            }
        }

        // all waves: DMA-stage the group's 16 h rows (32 x 1KB chunks)
        const unsigned short* __restrict__ hc =
            hrot + (size_t)t * (BB * UU) + (size_t)r0 * UU;
#pragma unroll
        for (int j = 0; j < 8; ++j) {
            int p = gi * 8 + j;
            int row = p >> 1, half = p & 1;
            __builtin_amdgcn_global_load_lds(
                (const void*)(hc + (size_t)row * 1024 + half * 512 + (size_t)lane * 8),
                (void*)&hls[row * 1032 + half * 512], 16, 0, 16);
        }
        asm volatile("s_waitcnt vmcnt(0)" ::: "memory");
        __syncthreads();

        // 32 MFMAs, two independent chains
        f32x4 acc0 = (f32x4){0.f, 0.f, 0.f, 0.f};
        f32x4 acc1 = (f32x4){0.f, 0.f, 0.f, 0.f};
#pragma unroll
        for (int kg = 0; kg < 32; kg += 2) {
            short8 a0 = *reinterpret_cast<const short8*>(&hls[aoff + kg * 32]);
            short8 a1 = *reinterpret_cast<const short8*>(&hls[aoff + kg * 32 + 32]);
            acc0 = __builtin_amdgcn_mfma_f32_16x16x32_bf16(a0, bfr[kg], acc0, 0, 0, 0);
            acc1 = __builtin_amdgcn_mfma_f32_16x16x32_bf16(a1, bfr[kg + 1], acc1, 0, 0, 0);
        }
        acc0[0] += acc1[0]; acc0[1] += acc1[1];
        acc0[2] += acc1[2]; acc0[3] += acc1[3];

#pragma unroll
        for (int r = 0; r < 4; ++r)
            gbuf[gi][(lane >> 4) * 4 + r][lane & 15] = acc0[r];
        __syncthreads();

        // wave 0: full elementwise tail (4 cells per lane, one row each)
        if (gi == 0) {
            float h1v[4], oo[4];
            union { unsigned short s[4]; unsigned long long q; } hp;
#pragma unroll
            for (int j = 0; j < 4; ++j) {
                int c = cb + j;
                float gf  = gbuf[0][trow][c] + xvv[0][j];
                float gii = gbuf[1][trow][c] + xvv[1][j];
                float gc  = gbuf[2][trow][c] + xvv[2][j];
                float go  = gbuf[3][trow][c] + xvv[3][j];
                float f  = 1.0f / (1.0f + __expf(-gf));
                float ii = 1.0f / (1.0f + __expf(-gii));
                float cc = tanhf(gc);
                oo[j] = 1.0f / (1.0f + __expf(-go));
                float h1 = f * h_own[j] + ii * cc;
                h_own[j] = h1;
                h1v[j] = h1;
                hp.s[j] = f2bf(h1);
            }
            if (t < TT - 1) {
                unsigned short* dst = hrot + (size_t)(t + 1) * (BB * UU)
                                      + (size_t)(r0 + trow) * UU + u0 + cb;
                __hip_atomic_store(reinterpret_cast<unsigned long long*>(dst), hp.q,
                                   __ATOMIC_RELAXED, __HIP_MEMORY_SCOPE_AGENT);
                asm volatile("s_waitcnt vmcnt(0)" ::: "memory");
                if (lane == 0)
                    __hip_atomic_store(flg + ((size_t)(t + 1) * 4 + mz) * 64 + ub, 1,
                                       __ATOMIC_RELAXED, __HIP_MEMORY_SCOPE_AGENT);
            }
            // y off the critical path
            f32x4 yv;
#pragma unroll
            for (int j = 0; j < 4; ++j) yv[j] = oo[j] * tanhf(h1v[j]);
            *reinterpret_cast<f32x4*>(
                y + ((size_t)(r0 + trow) * TT + t) * UU + u0 + cb) = yv;
        }
    }
}

// ---------------------------------------------------------------------------
template <typename XT>
static void run_pipeline(const float* x,
                         const float* fw, const float* fu, const float* fb,
                         const float* iw, const float* iu, const float* ib,
                         const float* cw, const float* cu, const float* cb,
                         const float* ow, const float* ou, const float* ob,
                         const float* h0, float* y, char* wsb, hipStream_t stream)
{
    const size_t xw_elems = (size_t)TT * BB * 4 * UU;       // 134,217,728
    const size_t pk_elems = (size_t)4 * 1024 * 1024;        // shorts per packed W
    const size_t hrot_elems = (size_t)(TT + 1) * BB * UU;
    const size_t xw_bytes = xw_elems * sizeof(XT);

    XT* xw = (XT*)wsb;
    short* upk = (short*)(wsb + xw_bytes);
    short* wpk = upk + pk_elems;
    unsigned short* hrot = (unsigned short*)(wpk + pk_elems);
    int* flg = (int*)(hrot + hrot_elems);

    pack_w<<<2048, 256, 0, stream>>>(fu, iu, cu, ou, upk);
    pack_w<<<2048, 256, 0, stream>>>(fw, iw, cw, ow, wpk);
    init_hbf<<<256, 256, 0, stream>>>(h0, hrot);
    gemm_xw<XT><<<dim3(32, 256), 256, 0, stream>>>(x, wpk, fb, ib, cb, ob, xw);
    hipMemsetAsync(flg, 0, (size_t)(TT + 1) * 4 * 64 * sizeof(int), stream);

    lstm_scan<XT><<<256, 256, 0, stream>>>(xw, h0, hrot, upk, y, flg);
}

extern "C" void kernel_launch(void* const* d_in, const int* in_sizes, int n_in,
                              void* d_out, int out_size, void* d_ws, size_t ws_size,
                              hipStream_t stream)
{
    const float* x  = (const float*)d_in[0];
    const float* fw = (const float*)d_in[1];
    const float* fu = (const float*)d_in[2];
    const float* fb = (const float*)d_in[3];
    const float* iw = (const float*)d_in[4];
    const float* iu = (const float*)d_in[5];
    const float* ib = (const float*)d_in[6];
    const float* cw = (const float*)d_in[7];
    const float* cu = (const float*)d_in[8];
    const float* cb = (const float*)d_in[9];
    const float* ow = (const float*)d_in[10];
    const float* ou = (const float*)d_in[11];
    const float* ob = (const float*)d_in[12];
    const float* h0 = (const float*)d_in[13];
    float* y = (float*)d_out;

    const size_t xw_elems = (size_t)TT * BB * 4 * UU;
    const size_t fixed = (size_t)16 * 1024 * 1024            // upk + wpk
                       + (size_t)(TT + 1) * BB * UU * 2      // hrot
                       + (size_t)(TT + 1) * 4 * 64 * 4 + 4096;
    const size_t f32_need = xw_elems * 4 + fixed;

    if (ws_size >= f32_need)
        run_pipeline<float>(x, fw, fu, fb, iw, iu, ib, cw, cu, cb, ow, ou, ob, h0, y,
                            (char*)d_ws, stream);
    else
        run_pipeline<unsigned short>(x, fw, fu, fb, iw, iu, ib, cw, cu, cb, ow, ou, ob, h0, y,
                                     (char*)d_ws, stream);
}

// Round 10
// 2907.566 us; speedup vs baseline: 1.1309x; 1.1309x over previous
//
#include <hip/hip_runtime.h>
#include <hip/hip_bf16.h>
#include <type_traits>

#define BB 64
#define TT 512
#define DD 1024
#define UU 1024

typedef __attribute__((ext_vector_type(8))) short short8;
typedef __attribute__((ext_vector_type(4))) float f32x4;

static __device__ __forceinline__ unsigned short f2bf(float f) {
    unsigned int u = __float_as_uint(f);
    unsigned int r = (u + 0x7fffu + ((u >> 16) & 1u)) >> 16;   // RNE
    return (unsigned short)r;
}
static __device__ __forceinline__ float bf2f(unsigned short s) {
    return __uint_as_float(((unsigned int)s) << 16);
}

template <typename XT>
static __device__ __forceinline__ float xwld(const XT* p, size_t i) {
    if constexpr (std::is_same<XT, float>::value) return p[i];
    else return bf2f((unsigned short)p[i]);
}

// ---------------------------------------------------------------------------
// Pack a logical (1024 x 4096) weight [k][gate*1024+u] into MFMA B-fragment
// layout: out[((n16*32 + kb)*64 + lane)*8 + i] =
//         W[kb*32 + (lane>>4)*8 + i][n16*16 + (lane&15)]
// ---------------------------------------------------------------------------
__global__ __launch_bounds__(256) void pack_w(
    const float* __restrict__ w0, const float* __restrict__ w1,
    const float* __restrict__ w2, const float* __restrict__ w3,
    short* __restrict__ out)
{
    int tid = blockIdx.x * 256 + threadIdx.x;   // 524288 threads
    int lane = tid & 63;
    int kb = (tid >> 6) & 31;
    int n16 = tid >> 11;
    int col = (n16 << 4) + (lane & 15);
    int g = col >> 10, u = col & 1023;
    const float* __restrict__ src = (g == 0) ? w0 : (g == 1) ? w1 : (g == 2) ? w2 : w3;
    int kbase = kb * 32 + ((lane >> 4) << 3);
    short8 p;
#pragma unroll
    for (int i = 0; i < 8; ++i) p[i] = (short)f2bf(src[(size_t)(kbase + i) * UU + u]);
    *reinterpret_cast<short8*>(out + (size_t)tid * 8) = p;
}

// ---------------------------------------------------------------------------
__global__ __launch_bounds__(256) void init_hbf(const float* __restrict__ h0,
                                                unsigned short* __restrict__ hb)
{
    int i = blockIdx.x * 256 + threadIdx.x;  // 65536
    hb[i] = f2bf(h0[i & (UU - 1)]);
}

// ---------------------------------------------------------------------------
// Phase 1: xw = x @ [fw|iw|cw|ow] + bias, MFMA bf16.
// Output layout: xw[t][ublk(64)][b(64)][g(4)][u16(16)]
// ---------------------------------------------------------------------------
template <typename XT>
__global__ __launch_bounds__(256) void gemm_xw(
    const float* __restrict__ x, const short* __restrict__ wpk,
    const float* __restrict__ fb, const float* __restrict__ ib,
    const float* __restrict__ cb, const float* __restrict__ ob,
    XT* __restrict__ xw)
{
    __shared__ short As[128 * 40];   // 128 rows x (32 + 8 pad) bf16
    __shared__ short Bs[8 * 512];    // 8 n16-tiles x 512

    const int tid = threadIdx.x;
    const int lane = tid & 63;
    const int wid = tid >> 6;
    const int wr = wid >> 1, wc = wid & 1;
    const int n0 = blockIdx.x << 7;
    const int m0 = blockIdx.y << 7;
    const int n16b = n0 >> 4;

    const int srow = tid >> 1;
    const int kh = tid & 1;
    const float* __restrict__ xrow = x + (size_t)(m0 + srow) * DD + kh * 16;
    const short* __restrict__ wsrc =
        wpk + ((size_t)(n16b + (tid >> 5)) * 32) * 512 + (size_t)(tid & 31) * 16;

    f32x4 acc[4][4];
#pragma unroll
    for (int i = 0; i < 4; ++i)
#pragma unroll
        for (int j = 0; j < 4; ++j) acc[i][j] = (f32x4){0.f, 0.f, 0.f, 0.f};

    const int aoff = (wr * 64 + (lane & 15)) * 40 + (lane >> 4) * 8;
    const int boff = (wc * 4) * 512 + lane * 8;

    for (int kb = 0; kb < 32; ++kb) {
        const float4* xp = reinterpret_cast<const float4*>(xrow + kb * 32);
        float4 v0 = xp[0], v1 = xp[1], v2 = xp[2], v3 = xp[3];
        short8 p0, p1;
        p0[0] = (short)f2bf(v0.x); p0[1] = (short)f2bf(v0.y);
        p0[2] = (short)f2bf(v0.z); p0[3] = (short)f2bf(v0.w);
        p0[4] = (short)f2bf(v1.x); p0[5] = (short)f2bf(v1.y);
        p0[6] = (short)f2bf(v1.z); p0[7] = (short)f2bf(v1.w);
        p1[0] = (short)f2bf(v2.x); p1[1] = (short)f2bf(v2.y);
        p1[2] = (short)f2bf(v2.z); p1[3] = (short)f2bf(v2.w);
        p1[4] = (short)f2bf(v3.x); p1[5] = (short)f2bf(v3.y);
        p1[6] = (short)f2bf(v3.z); p1[7] = (short)f2bf(v3.w);
        *reinterpret_cast<short8*>(&As[srow * 40 + kh * 16]) = p0;
        *reinterpret_cast<short8*>(&As[srow * 40 + kh * 16 + 8]) = p1;

        const short8* ws8 = reinterpret_cast<const short8*>(wsrc + (size_t)kb * 512);
        short8 b0v = ws8[0], b1v = ws8[1];
        *reinterpret_cast<short8*>(&Bs[tid * 16]) = b0v;
        *reinterpret_cast<short8*>(&Bs[tid * 16 + 8]) = b1v;
        __syncthreads();

        short8 af[4], bfr[4];
#pragma unroll
        for (int fi = 0; fi < 4; ++fi)
            af[fi] = *reinterpret_cast<const short8*>(&As[aoff + fi * 640]);
#pragma unroll
        for (int fj = 0; fj < 4; ++fj)
            bfr[fj] = *reinterpret_cast<const short8*>(&Bs[boff + fj * 512]);
#pragma unroll
        for (int fi = 0; fi < 4; ++fi)
#pragma unroll
            for (int fj = 0; fj < 4; ++fj)
                acc[fi][fj] = __builtin_amdgcn_mfma_f32_16x16x32_bf16(
                    af[fi], bfr[fj], acc[fi][fj], 0, 0, 0);
        __syncthreads();
    }

    const int g = n0 >> 10;
    const float* __restrict__ bias = (g == 0) ? fb : (g == 1) ? ib : (g == 2) ? cb : ob;
#pragma unroll
    for (int fi = 0; fi < 4; ++fi) {
#pragma unroll
        for (int fj = 0; fj < 4; ++fj) {
            int n = n0 + wc * 64 + fj * 16 + (lane & 15);
            int uc = n & 1023;
            int ub = uc >> 4, ul = uc & 15;
            float bv = bias[uc];
#pragma unroll
            for (int r = 0; r < 4; ++r) {
                int row = m0 + wr * 64 + fi * 16 + (lane >> 4) * 4 + r;
                int b = row >> 9, t = row & 511;
                float v = acc[fi][fj][r] + bv;
                size_t off = (((size_t)t * 64 + ub) * BB + b) * 64 + g * 16 + ul;
                if constexpr (std::is_same<XT, float>::value) xw[off] = v;
                else xw[off] = (XT)f2bf(v);
            }
        }
    }
}

// ---------------------------------------------------------------------------
// One r6-protocol scan step for one chain (macro so all LDS arrays stay
// directly in scope -> identical codegen to the proven r6 kernel).
// Protocol: [poll(wave0) -> sync] -> xw loads -> all-wave DMA -> vmcnt ->
// sync -> MFMA -> gbuf -> sync -> tail(+y) -> sync -> wave0 store+drain+flag.
// ---------------------------------------------------------------------------
#define CHAIN_STEP(MZ, R0, HLS, GBUF, HSH, HOWN)                                   \
  do {                                                                             \
    if (t > 0) {                                                                   \
      if (gi == 0) {                                                               \
        const int* fl = flg + ((size_t)t * 4 + (MZ)) * 64 + lane;                  \
        while (__hip_atomic_load(fl, __ATOMIC_RELAXED,                             \
                                 __HIP_MEMORY_SCOPE_AGENT) == 0)                   \
          __builtin_amdgcn_s_sleep(1);                                             \
      }                                                                            \
      __syncthreads();                                                             \
    }                                                                              \
    const XT* __restrict__ xp =                                                    \
        xw + ((size_t)t * 64 + ub) * 4096 + (size_t)((R0) + trow) * 64;            \
    float xv0 = xwld(xp, (size_t)0 * 16 + tcol);                                   \
    float xv1 = xwld(xp, (size_t)1 * 16 + tcol);                                   \
    float xv2 = xwld(xp, (size_t)2 * 16 + tcol);                                   \
    float xv3 = xwld(xp, (size_t)3 * 16 + tcol);                                   \
    const unsigned short* __restrict__ hc =                                        \
        hrot + (size_t)t * (BB * UU) + (size_t)(R0) * UU;                          \
    _Pragma("unroll")                                                              \
    for (int j = 0; j < 8; ++j) {                                                  \
      int p = gi * 8 + j;                                                          \
      int row = p >> 1, half = p & 1;                                              \
      __builtin_amdgcn_global_load_lds(                                            \
          (const void*)(hc + (size_t)row * 1024 + half * 512 + (size_t)lane * 8),  \
          (void*)&HLS[row * 1032 + half * 512], 16, 0, 16);                        \
    }                                                                              \
    asm volatile("s_waitcnt vmcnt(0)" ::: "memory");                               \
    __syncthreads();                                                               \
    f32x4 acc0 = (f32x4){0.f, 0.f, 0.f, 0.f};                                      \
    f32x4 acc1 = (f32x4){0.f, 0.f, 0.f, 0.f};                                      \
    _Pragma("unroll")                                                              \
    for (int kg = 0; kg < 32; kg += 2) {                                           \
      short8 a0 = *reinterpret_cast<const short8*>(&HLS[aoff + kg * 32]);          \
      short8 a1 = *reinterpret_cast<const short8*>(&HLS[aoff + kg * 32 + 32]);     \
      acc0 = __builtin_amdgcn_mfma_f32_16x16x32_bf16(a0, bfr[kg], acc0, 0, 0, 0);  \
      acc1 = __builtin_amdgcn_mfma_f32_16x16x32_bf16(a1, bfr[kg + 1], acc1,        \
                                                     0, 0, 0);                     \
    }                                                                              \
    acc0[0] += acc1[0]; acc0[1] += acc1[1];                                        \
    acc0[2] += acc1[2]; acc0[3] += acc1[3];                                        \
    _Pragma("unroll")                                                              \
    for (int r = 0; r < 4; ++r)                                                    \
      GBUF[gi][(lane >> 4) * 4 + r][lane & 15] = acc0[r];                          \
    __syncthreads();                                                               \
    {                                                                              \
      float gf  = GBUF[0][trow][tcol] + xv0;                                       \
      float gii = GBUF[1][trow][tcol] + xv1;                                       \
      float gc  = GBUF[2][trow][tcol] + xv2;                                       \
      float go  = GBUF[3][trow][tcol] + xv3;                                       \
      float f   = 1.0f / (1.0f + __expf(-gf));                                     \
      float ii  = 1.0f / (1.0f + __expf(-gii));                                    \
      float cc  = tanhf(gc);                                                       \
      float oo  = 1.0f / (1.0f + __expf(-go));                                     \
      float h1  = f * (HOWN) + ii * cc;                                            \
      (HOWN) = h1;                                                                 \
      y[((size_t)((R0) + trow) * TT + t) * UU + u0 + tcol] = oo * tanhf(h1);       \
      if (t < TT - 1) HSH[trow][tcol] = f2bf(h1);                                  \
    }                                                                              \
    if (t < TT - 1) {                                                              \
      __syncthreads();                                                             \
      if (gi == 0) {                                                               \
        int row = lane >> 2, c4 = (lane & 3) << 2;                                 \
        unsigned long long pv =                                                    \
            *reinterpret_cast<unsigned long long*>(&HSH[row][c4]);                 \
        unsigned short* dst = hrot + (size_t)(t + 1) * (BB * UU)                   \
                              + (size_t)((R0) + row) * UU + u0 + c4;               \
        __hip_atomic_store(reinterpret_cast<unsigned long long*>(dst), pv,         \
                           __ATOMIC_RELAXED, __HIP_MEMORY_SCOPE_AGENT);            \
        asm volatile("s_waitcnt vmcnt(0)" ::: "memory");                           \
        if (lane == 0)                                                             \
          __hip_atomic_store(flg + ((size_t)(t + 1) * 4 + (MZ)) * 64 + ub, 1,      \
                             __ATOMIC_RELAXED, __HIP_MEMORY_SCOPE_AGENT);          \
      }                                                                            \
    }                                                                              \
  } while (0)

// ---------------------------------------------------------------------------
// Phase 2: persistent scan, TWO independent recurrence chains per block.
// Grid 128 = 2 chain-pairs (z) x 64 u-blocks. Block (z,ub) runs chains
// mz=2z (rows 32z..32z+15) and mz=2z+1 (rows 32z+16..+31) for u cols
// u0..u0+15, all 4 gates (wave=gate; B-frags shared by both chains).
// Chain A's produce->detect handoff propagates during chain B's compute
// phase and vice versa -- MALL latency hidden, per-chain protocol = r6.
// ---------------------------------------------------------------------------
template <typename XT>
__global__ __launch_bounds__(256, 1) void lstm_scan(
    const XT* __restrict__ xw, const float* __restrict__ h0,
    unsigned short* __restrict__ hrot,     // [TT+1][64][1024] bf16 rotating
    const short* __restrict__ upk,
    float* __restrict__ y, int* __restrict__ flg)   // [TT+1][4][64]
{
    __shared__ unsigned short hlsA[16 * 1032 + 8];
    __shared__ unsigned short hlsB[16 * 1032 + 8];
    __shared__ float gbufA[4][16][20];
    __shared__ float gbufB[4][16][20];
    __shared__ unsigned short hshA[16][16];
    __shared__ unsigned short hshB[16][16];

    const int tid = threadIdx.x;
    const int lane = tid & 63;
    const int gi = tid >> 6;              // wave = gate
    const int z  = blockIdx.x >> 6;       // chain pair 0..1
    const int ub = blockIdx.x & 63;       // u column-block
    const int mzA = z * 2, mzB = z * 2 + 1;
    const int r0A = mzA << 4, r0B = mzB << 4;
    const int u0 = ub << 4;

    // B-fragments for (gate gi, n16 = gi*64+ub) -- shared by both chains
    const short* __restrict__ bsrc =
        upk + ((size_t)(gi * 64 + ub) * 32) * 512 + (size_t)lane * 8;
    short8 bfr[32];
#pragma unroll
    for (int kb = 0; kb < 32; ++kb)
        bfr[kb] = *reinterpret_cast<const short8*>(bsrc + (size_t)kb * 512);

    const int aoff = (lane & 15) * 1032 + (lane >> 4) * 8;  // LDS A-frag (shorts)
    const int trow = tid >> 4, tcol = tid & 15;             // tail cell

    float h_ownA = h0[u0 + tcol];
    float h_ownB = h_ownA;

    for (int t = 0; t < TT; ++t) {
        CHAIN_STEP(mzA, r0A, hlsA, gbufA, hshA, h_ownA);
        CHAIN_STEP(mzB, r0B, hlsB, gbufB, hshB, h_ownB);
    }
}

// ---------------------------------------------------------------------------
template <typename XT>
static void run_pipeline(const float* x,
                         const float* fw, const float* fu, const float* fb,
                         const float* iw, const float* iu, const float* ib,
                         const float* cw, const float* cu, const float* cb,
                         const float* ow, const float* ou, const float* ob,
                         const float* h0, float* y, char* wsb, hipStream_t stream)
{
    const size_t xw_elems = (size_t)TT * BB * 4 * UU;       // 134,217,728
    const size_t pk_elems = (size_t)4 * 1024 * 1024;        // shorts per packed W
    const size_t hrot_elems = (size_t)(TT + 1) * BB * UU;
    const size_t xw_bytes = xw_elems * sizeof(XT);

    XT* xw = (XT*)wsb;
    short* upk = (short*)(wsb + xw_bytes);
    short* wpk = upk + pk_elems;
    unsigned short* hrot = (unsigned short*)(wpk + pk_elems);
    int* flg = (int*)(hrot + hrot_elems);

    pack_w<<<2048, 256, 0, stream>>>(fu, iu, cu, ou, upk);
    pack_w<<<2048, 256, 0, stream>>>(fw, iw, cw, ow, wpk);
    init_hbf<<<256, 256, 0, stream>>>(h0, hrot);
    gemm_xw<XT><<<dim3(32, 256), 256, 0, stream>>>(x, wpk, fb, ib, cb, ob, xw);
    hipMemsetAsync(flg, 0, (size_t)(TT + 1) * 4 * 64 * sizeof(int), stream);

    lstm_scan<XT><<<128, 256, 0, stream>>>(xw, h0, hrot, upk, y, flg);
}

extern "C" void kernel_launch(void* const* d_in, const int* in_sizes, int n_in,
                              void* d_out, int out_size, void* d_ws, size_t ws_size,
                              hipStream_t stream)
{
    const float* x  = (const float*)d_in[0];
    const float* fw = (const float*)d_in[1];
    const float* fu = (const float*)d_in[2];
    const float* fb = (const float*)d_in[3];
    const float* iw = (const float*)d_in[4];
    const float* iu = (const float*)d_in[5];
    const float* ib = (const float*)d_in[6];
    const float* cw = (const float*)d_in[7];
    const float* cu = (const float*)d_in[8];
    const float* cb = (const float*)d_in[9];
    const float* ow = (const float*)d_in[10];
    const float* ou = (const float*)d_in[11];
    const float* ob = (const float*)d_in[12];
    const float* h0 = (const float*)d_in[13];
    float* y = (float*)d_out;

    const size_t xw_elems = (size_t)TT * BB * 4 * UU;
    const size_t fixed = (size_t)16 * 1024 * 1024            // upk + wpk
                       + (size_t)(TT + 1) * BB * UU * 2      // hrot
                       + (size_t)(TT + 1) * 4 * 64 * 4 + 4096;
    const size_t f32_need = xw_elems * 4 + fixed;

    if (ws_size >= f32_need)
        run_pipeline<float>(x, fw, fu, fb, iw, iu, ib, cw, cu, cb, ow, ou, ob, h0, y,
                            (char*)d_ws, stream);
    else
        run_pipeline<unsigned short>(x, fw, fu, fb, iw, iu, ib, cw, cu, cb, ow, ou, ob, h0, y,
                                     (char*)d_ws, stream);
}